// Round 4
// baseline (721.089 us; speedup 1.0000x reference)
//
#include <hip/hip_runtime.h>
#include <math.h>

#define NNODES 50000
#define NEDGES 800000
#define FIN    1433
#define KP1    1472   // FIN padded to multiple of 64
#define HDIM   256
#define NCLS   7
#define MPAD   50048  // NNODES padded to multiple of 64

typedef __attribute__((ext_vector_type(8))) short short8;
typedef __attribute__((ext_vector_type(4))) float f32x4;

__device__ __forceinline__ unsigned short f2bf(float f) {
    unsigned u = __builtin_bit_cast(unsigned, f);
    u += 0x7fffu + ((u >> 16) & 1u);          // round-to-nearest-even
    return (unsigned short)(u >> 16);
}

__device__ __forceinline__ float bf2f(unsigned short u) {
    unsigned v = ((unsigned)u) << 16;
    return __builtin_bit_cast(float, v);
}

__device__ __forceinline__ void gl2lds16(const void* g, void* l) {
    __builtin_amdgcn_global_load_lds(
        (const __attribute__((address_space(1))) unsigned int*)g,
        (__attribute__((address_space(3))) unsigned int*)l, 16, 0, 0);
}

// unaligned-safe 16 B load (X rows are only 4 B aligned: FIN=1433)
__device__ __forceinline__ f32x4 ld4u(const float* p) {
    f32x4 v; __builtin_memcpy(&v, p, 16); return v;
}

// ---------------- CSR count + weight transpose/cast, one launch ----------------

#define NB_COUNT 3125   // ceil(NEDGES/256)
#define NB_CAST  1728   // ceil((HDIM*KP1 + HDIM*HDIM)/256)

__global__ void count_cast(const int* __restrict__ col, int* __restrict__ cnt,
                           const float* __restrict__ W1, const float* __restrict__ W2,
                           unsigned short* __restrict__ w1t, unsigned short* __restrict__ w2t) {
    int b = blockIdx.x;
    if (b < NB_COUNT) {
        int e = b * 256 + threadIdx.x;
        if (e < NEDGES) atomicAdd(&cnt[col[e]], 1);
    } else {
        int idx = (b - NB_COUNT) * 256 + threadIdx.x;
        if (idx < HDIM * KP1) {
            int n = idx / KP1, k = idx % KP1;
            w1t[idx] = f2bf((k < FIN) ? W1[(size_t)k * HDIM + n] : 0.f);
        } else {
            int j = idx - HDIM * KP1;
            if (j < HDIM * HDIM) {
                int n = j / HDIM, k = j % HDIM;
                w2t[j] = f2bf(W2[(size_t)k * HDIM + n]);
            }
        }
    }
}

// 3-stage parallel scan
#define SCAN_BS 512

__global__ __launch_bounds__(SCAN_BS) void scan_part(const int* __restrict__ cnt,
                                                     int* __restrict__ bsum, int n) {
    __shared__ int red[SCAN_BS];
    int t = threadIdx.x;
    int i = blockIdx.x * SCAN_BS + t;
    red[t] = (i < n) ? cnt[i] : 0;
    __syncthreads();
    for (int off = SCAN_BS / 2; off > 0; off >>= 1) {
        if (t < off) red[t] += red[t + off];
        __syncthreads();
    }
    if (t == 0) bsum[blockIdx.x] = red[0];
}

__global__ __launch_bounds__(128) void scan_top(int* __restrict__ bsum, int nb) {
    __shared__ int s[128];
    int t = threadIdx.x;
    int v = (t < nb) ? bsum[t] : 0;
    s[t] = v;
    __syncthreads();
    for (int off = 1; off < 128; off <<= 1) {
        int u = (t >= off) ? s[t - off] : 0;
        __syncthreads();
        s[t] += u;
        __syncthreads();
    }
    if (t < nb) bsum[t] = s[t] - v;            // exclusive
}

__global__ __launch_bounds__(SCAN_BS) void scan_apply(const int* __restrict__ cnt,
                                                      const int* __restrict__ bsum,
                                                      int* __restrict__ rp,
                                                      float* __restrict__ dinv,
                                                      int n, int total) {
    __shared__ int s[SCAN_BS];
    int t = threadIdx.x;
    int i = blockIdx.x * SCAN_BS + t;
    int v = (i < n) ? cnt[i] : 0;
    s[t] = v;
    __syncthreads();
    for (int off = 1; off < SCAN_BS; off <<= 1) {
        int u = (t >= off) ? s[t - off] : 0;
        __syncthreads();
        s[t] += u;
        __syncthreads();
    }
    if (i < n) {
        rp[i] = bsum[blockIdx.x] + s[t] - v;   // exclusive prefix
        dinv[i] = rsqrtf((float)(v + 1));
    }
    if (i == n) rp[n] = total;
}

// fill + per-edge weight precompute, packed {src, weight} per edge (one 8 B store)
__global__ void fill_kernel(const int* __restrict__ row, const int* __restrict__ col,
                            const int* __restrict__ rp, int* __restrict__ cur,
                            int2* __restrict__ csrw,
                            const float* __restrict__ dinv, int E) {
    int e = blockIdx.x * blockDim.x + threadIdx.x;
    if (e < E) {
        int c = col[e], r = row[e];
        int pos = rp[c] + atomicAdd(&cur[c], 1);
        csrw[pos] = make_int2(r, __float_as_int(dinv[r] * dinv[c]));
    }
}

// ---------------- layer-1 GEMM (round-2 verified form: single-buffer, 1-deep X prefetch)

__global__ __launch_bounds__(256) void gemm1_fused(const float* __restrict__ X,
                                                   const unsigned short* __restrict__ Bt,
                                                   unsigned short* __restrict__ C) {
    __shared__ __align__(16) unsigned short As[64 * 64];    // 8 KB
    __shared__ __align__(16) unsigned short Bs[256 * 64];   // 32 KB
    const int tid = threadIdx.x;
    const int wave = tid >> 6, lane = tid & 63;
    const int m0 = blockIdx.x * 64;
    const int wn = wave * 64;
    const int kq = lane >> 4, l16 = lane & 15;
    const int lq = lane >> 4;      // row within 4-row group
    const int h  = lane & 15;      // k-quad index, 16 per row

    int rowbase[4];
    #pragma unroll
    for (int i = 0; i < 4; ++i) {
        int r = m0 + wave * 16 + i * 4 + lq;
        if (r >= NNODES) r = NNODES - 1;       // clamp: in-bounds, filtered at store
        rowbase[i] = r * FIN;
    }
    // LDS write offsets: row r = wave*16 + i*4 + lq -> r&7 = lq + 4*(i&1)
    int aw[4];
    #pragma unroll
    for (int i = 0; i < 4; ++i) {
        int r7 = lq + 4 * (i & 1);
        aw[i] = (wave * 16 + i * 4 + lq) * 64 + (((h >> 1) ^ r7) * 8) + (h & 1) * 4;
    }

    int bo[8];
    #pragma unroll
    for (int i = 0; i < 8; ++i) {
        int c = i * 256 + tid;                 // LDS chunk = linear c
        int n = c >> 3, ccg = (c & 7) ^ (n & 7);
        bo[i] = n * KP1 + ccg * 8;             // permuted global chunk
    }

    int aoffb[2], boffb[2];
    #pragma unroll
    for (int ks = 0; ks < 2; ++ks) {
        int swz = ((ks * 4 + kq) ^ (l16 & 7)) * 8;
        aoffb[ks] = l16 * 64 + swz;
        boffb[ks] = (wn + l16) * 64 + swz;
    }

    f32x4 acc[4][4] = {};
    constexpr int NT = KP1 / 64;               // 23 chunks; only the last crosses FIN

    f32x4 fv[4];
    #pragma unroll
    for (int i = 0; i < 4; ++i) fv[i] = ld4u(&X[rowbase[i] + h * 4]);   // chunk 0, k<64

    for (int t = 0; t < NT; ++t) {
        const int k0 = t * 64;
        #pragma unroll
        for (int i = 0; i < 8; ++i)
            gl2lds16(Bt + bo[i] + k0, &Bs[(i * 256 + tid) * 8]);
        #pragma unroll
        for (int i = 0; i < 4; ++i) {
            ushort4 pk = make_ushort4(f2bf(fv[i].x), f2bf(fv[i].y),
                                      f2bf(fv[i].z), f2bf(fv[i].w));
            *(ushort4*)&As[aw[i]] = pk;
        }
        __syncthreads();

        // prefetch chunk t+1 while the MFMAs below run (uniform branch)
        f32x4 nv[4];
        const bool more = (t + 1 < NT);
        if (more) {
            const int kb = k0 + 64 + h * 4;
            if (t + 2 == NT) {                 // last chunk: kb may reach 1468 >= FIN
                #pragma unroll
                for (int i = 0; i < 4; ++i) {
                    float a = (kb + 0 < FIN) ? X[rowbase[i] + kb + 0] : 0.f;
                    float b = (kb + 1 < FIN) ? X[rowbase[i] + kb + 1] : 0.f;
                    float c = (kb + 2 < FIN) ? X[rowbase[i] + kb + 2] : 0.f;
                    float d = (kb + 3 < FIN) ? X[rowbase[i] + kb + 3] : 0.f;
                    nv[i] = (f32x4){a, b, c, d};
                }
            } else {
                #pragma unroll
                for (int i = 0; i < 4; ++i) nv[i] = ld4u(&X[rowbase[i] + kb]);
            }
        }

        #pragma unroll
        for (int ks = 0; ks < 2; ++ks) {
            short8 af[4], bg[4];
            #pragma unroll
            for (int i = 0; i < 4; ++i) af[i] = *(const short8*)&As[i * 1024 + aoffb[ks]];
            #pragma unroll
            for (int j = 0; j < 4; ++j) bg[j] = *(const short8*)&Bs[j * 1024 + boffb[ks]];
            #pragma unroll
            for (int i = 0; i < 4; ++i)
                #pragma unroll
                for (int j = 0; j < 4; ++j)
                    acc[i][j] = __builtin_amdgcn_mfma_f32_16x16x32_bf16(af[i], bg[j], acc[i][j], 0, 0, 0);
        }
        __syncthreads();
        if (more) {
            #pragma unroll
            for (int i = 0; i < 4; ++i) fv[i] = nv[i];
        }
    }

    // C/D layout: col = lane&15, row = (lane>>4)*4 + reg
    #pragma unroll
    for (int i = 0; i < 4; ++i) {
        int gm_base = m0 + i * 16 + (lane >> 4) * 4;
        #pragma unroll
        for (int r = 0; r < 4; ++r) {
            int gm = gm_base + r;
            if (gm < NNODES) {
                #pragma unroll
                for (int j = 0; j < 4; ++j) {
                    int gn = wn + j * 16 + l16;
                    C[(size_t)gm * HDIM + gn] = f2bf(acc[i][j][r]);
                }
            }
        }
    }
}

// ---------------- layer-2 GEMM: bf16 A, all global_load_lds, BM=64 BN=256 BK=64 ----------

__global__ __launch_bounds__(256) void gemm2_lds(const unsigned short* __restrict__ A,
                                                 const unsigned short* __restrict__ Bt,
                                                 unsigned short* __restrict__ C) {
    __shared__ __align__(16) unsigned short As[64 * 64];
    __shared__ __align__(16) unsigned short Bs[256 * 64];
    const int tid = threadIdx.x;
    const int wave = tid >> 6, lane = tid & 63;
    const int m0 = blockIdx.x * 64;
    const int wn = wave * 64;
    const int kq = lane >> 4, l16 = lane & 15;

    int ao[2];
    #pragma unroll
    for (int i = 0; i < 2; ++i) {
        int c = i * 256 + tid;
        int m = c >> 3, ccg = (c & 7) ^ (m & 7);
        ao[i] = (m0 + m) * HDIM + ccg * 8;     // pad rows: finite poison, discarded at store
    }
    int bo[8];
    #pragma unroll
    for (int i = 0; i < 8; ++i) {
        int c = i * 256 + tid;
        int n = c >> 3, ccg = (c & 7) ^ (n & 7);
        bo[i] = n * HDIM + ccg * 8;
    }
    int aoffb[2], boffb[2];
    #pragma unroll
    for (int ks = 0; ks < 2; ++ks) {
        int swz = ((ks * 4 + kq) ^ (l16 & 7)) * 8;
        aoffb[ks] = l16 * 64 + swz;
        boffb[ks] = (wn + l16) * 64 + swz;
    }

    f32x4 acc[4][4] = {};
    #pragma unroll
    for (int k0 = 0; k0 < HDIM; k0 += 64) {
        #pragma unroll
        for (int i = 0; i < 2; ++i) gl2lds16(A + ao[i] + k0, &As[(i * 256 + tid) * 8]);
        #pragma unroll
        for (int i = 0; i < 8; ++i) gl2lds16(Bt + bo[i] + k0, &Bs[(i * 256 + tid) * 8]);
        __syncthreads();
        #pragma unroll
        for (int ks = 0; ks < 2; ++ks) {
            short8 af[4], bg[4];
            #pragma unroll
            for (int i = 0; i < 4; ++i) af[i] = *(const short8*)&As[i * 1024 + aoffb[ks]];
            #pragma unroll
            for (int j = 0; j < 4; ++j) bg[j] = *(const short8*)&Bs[j * 1024 + boffb[ks]];
            #pragma unroll
            for (int i = 0; i < 4; ++i)
                #pragma unroll
                for (int j = 0; j < 4; ++j)
                    acc[i][j] = __builtin_amdgcn_mfma_f32_16x16x32_bf16(af[i], bg[j], acc[i][j], 0, 0, 0);
        }
        __syncthreads();
    }

    #pragma unroll
    for (int i = 0; i < 4; ++i) {
        int gm_base = m0 + i * 16 + (lane >> 4) * 4;
        #pragma unroll
        for (int r = 0; r < 4; ++r) {
            int gm = gm_base + r;
            if (gm < NNODES) {
                #pragma unroll
                for (int j = 0; j < 4; ++j) {
                    int gn = wn + j * 16 + l16;
                    C[(size_t)gm * HDIM + gn] = f2bf(acc[i][j][r]);
                }
            }
        }
    }
}

// ---------------- half-wave paired aggregation -----------------------------------
// Lanes 0-31 gather even edges, 32-63 odd edges; 16 B (short8) per lane -> 1 KB and
// 2 edges per gather instruction (2x bytes-in-flight vs one-edge ushort4 scheme).
// Each half accumulates its edges for dims [hl*8, hl*8+8); combined at the end with
// one shfl_xor(32) per dim. Self-loop handled in the prologue (q=0 side), first edge
// on the q=1 side.

__device__ __forceinline__ void agg_pair(const short8* __restrict__ hh, int node,
                                         int hl, int q, float sw,
                                         int p, int p1,
                                         const int2* __restrict__ csrw,
                                         float acc[8]) {
    // prologue: q=0 -> self with weight sw; q=1 -> first edge (or dummy)
    int idx; float w;
    if (q == 0) { idx = node; w = sw; }
    else if (p < p1) { int2 e = csrw[p]; idx = e.x; w = __int_as_float(e.y); }
    else { idx = node; w = 0.f; }
    {
        short8 t = hh[idx * 32 + hl];
        #pragma unroll
        for (int d = 0; d < 8; ++d) acc[d] = w * bf2f((unsigned short)t[d]);
    }
    p += 1;                                    // q=1 consumed one edge
    // main: 8 pairs (16 edges) per batch
    for (; p + 16 <= p1; p += 16) {
        int2 e[8];
        #pragma unroll
        for (int j = 0; j < 8; ++j) e[j] = csrw[p + 2 * j + q];
        short8 t[8];
        #pragma unroll
        for (int j = 0; j < 8; ++j) t[j] = hh[e[j].x * 32 + hl];
        #pragma unroll
        for (int j = 0; j < 8; ++j) {
            float wj = __int_as_float(e[j].y);
            #pragma unroll
            for (int d = 0; d < 8; ++d) acc[d] += wj * bf2f((unsigned short)t[j][d]);
        }
    }
    // mid: 4 pairs (8 edges)
    if (p + 8 <= p1) {
        int2 e[4];
        #pragma unroll
        for (int j = 0; j < 4; ++j) e[j] = csrw[p + 2 * j + q];
        short8 t[4];
        #pragma unroll
        for (int j = 0; j < 4; ++j) t[j] = hh[e[j].x * 32 + hl];
        #pragma unroll
        for (int j = 0; j < 4; ++j) {
            float wj = __int_as_float(e[j].y);
            #pragma unroll
            for (int d = 0; d < 8; ++d) acc[d] += wj * bf2f((unsigned short)t[j][d]);
        }
        p += 8;
    }
    // tail: one pair per iteration
    for (; p < p1; p += 2) {
        int pe = p + q;
        int ix; float wj;
        if (pe < p1) { int2 e = csrw[pe]; ix = e.x; wj = __int_as_float(e.y); }
        else { ix = node; wj = 0.f; }
        short8 t = hh[ix * 32 + hl];
        #pragma unroll
        for (int d = 0; d < 8; ++d) acc[d] += wj * bf2f((unsigned short)t[d]);
    }
    // combine halves: both halves end with the full sum for dims hl*8..+8
    #pragma unroll
    for (int d = 0; d < 8; ++d) acc[d] += __shfl_xor(acc[d], 32);
}

// ---------------- aggregation layer 1 (bf16 in/out, + bias + relu) ---------

__global__ __launch_bounds__(256) void agg_kernel(const short8* __restrict__ hh,
                                                  short8* __restrict__ out,
                                                  const float* __restrict__ dinv,
                                                  const int* __restrict__ rp,
                                                  const int2* __restrict__ csrw,
                                                  const float* __restrict__ bias,
                                                  int n) {
    int node = blockIdx.x * 4 + (threadIdx.x >> 6);
    int lane = threadIdx.x & 63;
    if (node >= n) return;
    int hl = lane & 31, q = lane >> 5;
    float di = dinv[node];
    float acc[8];
    agg_pair(hh, node, hl, q, di * di, rp[node], rp[node + 1], csrw, acc);
    if (q == 0) {
        const float4* b4 = (const float4*)bias;
        float4 ba = b4[hl * 2], bb = b4[hl * 2 + 1];
        short8 pk;
        pk[0] = (short)f2bf(fmaxf(acc[0] + ba.x, 0.f));
        pk[1] = (short)f2bf(fmaxf(acc[1] + ba.y, 0.f));
        pk[2] = (short)f2bf(fmaxf(acc[2] + ba.z, 0.f));
        pk[3] = (short)f2bf(fmaxf(acc[3] + ba.w, 0.f));
        pk[4] = (short)f2bf(fmaxf(acc[4] + bb.x, 0.f));
        pk[5] = (short)f2bf(fmaxf(acc[5] + bb.y, 0.f));
        pk[6] = (short)f2bf(fmaxf(acc[6] + bb.z, 0.f));
        pk[7] = (short)f2bf(fmaxf(acc[7] + bb.w, 0.f));
        out[node * 32 + hl] = pk;
    }
}

// ---------------- aggregation layer 2 fused with mm3: h3p[N][8] (padded) ----------

__global__ __launch_bounds__(256) void agg2_mm3_kernel(const short8* __restrict__ hh,
                                                       float* __restrict__ h3p,
                                                       const float* __restrict__ dinv,
                                                       const int* __restrict__ rp,
                                                       const int2* __restrict__ csrw,
                                                       const float* __restrict__ bias,
                                                       const float* __restrict__ W3,
                                                       int n) {
    __shared__ __align__(16) float Ws[NCLS * HDIM];   // Ws[c*256 + k] = W3[k*7 + c]
    int tid = threadIdx.x;
    for (int i = tid; i < NCLS * HDIM; i += 256)
        Ws[i] = W3[(i & 255) * NCLS + (i >> 8)];
    __syncthreads();

    int node = blockIdx.x * 4 + (tid >> 6);
    int lane = tid & 63;
    if (node >= n) return;
    int hl = lane & 31, q = lane >> 5;
    float di = dinv[node];
    float acc[8];
    agg_pair(hh, node, hl, q, di * di, rp[node], rp[node + 1], csrw, acc);
    const float4* b4 = (const float4*)bias;
    float4 ba = b4[hl * 2], bb = b4[hl * 2 + 1];
    float a[8];
    a[0] = fmaxf(acc[0] + ba.x, 0.f); a[1] = fmaxf(acc[1] + ba.y, 0.f);
    a[2] = fmaxf(acc[2] + ba.z, 0.f); a[3] = fmaxf(acc[3] + ba.w, 0.f);
    a[4] = fmaxf(acc[4] + bb.x, 0.f); a[5] = fmaxf(acc[5] + bb.y, 0.f);
    a[6] = fmaxf(acc[6] + bb.z, 0.f); a[7] = fmaxf(acc[7] + bb.w, 0.f);

    // dims duplicated across halves -> full-64 reduce gives 2x the true sum
    float p7[NCLS];
    #pragma unroll
    for (int c = 0; c < NCLS; ++c) {
        const float4* w4 = (const float4*)&Ws[c * HDIM + hl * 8];
        float4 wa = w4[0], wb = w4[1];
        p7[c] = a[0] * wa.x + a[1] * wa.y + a[2] * wa.z + a[3] * wa.w
              + a[4] * wb.x + a[5] * wb.y + a[6] * wb.z + a[7] * wb.w;
    }
    #pragma unroll
    for (int c = 0; c < NCLS; ++c)
        for (int off = 32; off > 0; off >>= 1) p7[c] += __shfl_down(p7[c], off);
    if (lane == 0) {
        float4 lo = make_float4(0.5f * p7[0], 0.5f * p7[1], 0.5f * p7[2], 0.5f * p7[3]);
        float4 hi = make_float4(0.5f * p7[4], 0.5f * p7[5], 0.5f * p7[6], 0.f);
        *(float4*)&h3p[node * 8]     = lo;
        *(float4*)&h3p[node * 8 + 4] = hi;
    }
}

// ---------------- layer-3 aggregation + bias + log_softmax ----------------

__global__ void final_kernel(const float* __restrict__ h3p, const float* __restrict__ dinv,
                             const int* __restrict__ rp, const int2* __restrict__ csrw,
                             const float* __restrict__ b3, float* __restrict__ out, int n) {
    int i = blockIdx.x * blockDim.x + threadIdx.x;
    if (i >= n) return;
    const float4* H = (const float4*)h3p;
    float di = dinv[i];
    float sw = di * di;
    float4 su = H[i * 2], sv = H[i * 2 + 1];
    float a0 = sw * su.x, a1 = sw * su.y, a2 = sw * su.z, a3 = sw * su.w;
    float a4 = sw * sv.x, a5 = sw * sv.y, a6 = sw * sv.z;
    int p = rp[i], p1 = rp[i + 1];
    for (; p + 4 <= p1; p += 4) {
        int2 e0 = csrw[p], e1 = csrw[p + 1], e2 = csrw[p + 2], e3 = csrw[p + 3];
        float w0 = __int_as_float(e0.y), w1 = __int_as_float(e1.y);
        float w2 = __int_as_float(e2.y), w3 = __int_as_float(e3.y);
        float4 u0 = H[e0.x * 2], v0 = H[e0.x * 2 + 1];
        float4 u1 = H[e1.x * 2], v1 = H[e1.x * 2 + 1];
        float4 u2 = H[e2.x * 2], v2 = H[e2.x * 2 + 1];
        float4 u3 = H[e3.x * 2], v3 = H[e3.x * 2 + 1];
        a0 += w0 * u0.x + w1 * u1.x + w2 * u2.x + w3 * u3.x;
        a1 += w0 * u0.y + w1 * u1.y + w2 * u2.y + w3 * u3.y;
        a2 += w0 * u0.z + w1 * u1.z + w2 * u2.z + w3 * u3.z;
        a3 += w0 * u0.w + w1 * u1.w + w2 * u2.w + w3 * u3.w;
        a4 += w0 * v0.x + w1 * v1.x + w2 * v2.x + w3 * v3.x;
        a5 += w0 * v0.y + w1 * v1.y + w2 * v2.y + w3 * v3.y;
        a6 += w0 * v0.z + w1 * v1.z + w2 * v2.z + w3 * v3.z;
    }
    for (; p < p1; ++p) {
        int2 e = csrw[p];
        float wg = __int_as_float(e.y);
        float4 u = H[e.x * 2], v = H[e.x * 2 + 1];
        a0 += wg * u.x; a1 += wg * u.y; a2 += wg * u.z; a3 += wg * u.w;
        a4 += wg * v.x; a5 += wg * v.y; a6 += wg * v.z;
    }
    float acc[NCLS] = {a0, a1, a2, a3, a4, a5, a6};
    float mx = -1e30f;
    #pragma unroll
    for (int c = 0; c < NCLS; ++c) { acc[c] += b3[c]; mx = fmaxf(mx, acc[c]); }
    float sum = 0.f;
    #pragma unroll
    for (int c = 0; c < NCLS; ++c) sum += expf(acc[c] - mx);
    float lse = mx + logf(sum);
    #pragma unroll
    for (int c = 0; c < NCLS; ++c) out[i * NCLS + c] = acc[c] - lse;
}

// ---------------- launch ----------------

extern "C" void kernel_launch(void* const* d_in, const int* in_sizes, int n_in,
                              void* d_out, int out_size, void* d_ws, size_t ws_size,
                              hipStream_t stream) {
    const float* x  = (const float*)d_in[0];
    const int*   ei = (const int*)d_in[1];
    const float* W1 = (const float*)d_in[2];
    const float* b1 = (const float*)d_in[3];
    const float* W2 = (const float*)d_in[4];
    const float* b2 = (const float*)d_in[5];
    const float* W3 = (const float*)d_in[6];
    const float* b3 = (const float*)d_in[7];
    float* out = (float*)d_out;
    const int* row = ei;
    const int* col = ei + NEDGES;

    char* w = (char*)d_ws;
    auto alloc = [&](size_t b) { void* p = (void*)w; w += (b + 255) & ~(size_t)255; return p; };
    int*   cnt  = (int*)alloc(NNODES * 4);
    int*   cur  = (int*)alloc(NNODES * 4);   // contiguous with cnt (both 256-padded)
    int*   rp   = (int*)alloc((NNODES + 1) * 4);
    float* dinv = (float*)alloc(NNODES * 4);
    int*   bsum = (int*)alloc(128 * 4);
    int2*  csrw = (int2*)alloc((size_t)NEDGES * 8);
    unsigned short* w1t  = (unsigned short*)alloc((size_t)HDIM * KP1 * 2);
    unsigned short* w2t  = (unsigned short*)alloc((size_t)HDIM * HDIM * 2);
    unsigned short* h_bf = (unsigned short*)alloc((size_t)MPAD * HDIM * 2);
    unsigned short* a_bf = (unsigned short*)alloc((size_t)MPAD * HDIM * 2);
    float* h3p = (float*)alloc((size_t)NNODES * 8 * 4);

    const size_t cpad = ((size_t)NNODES * 4 + 255) & ~(size_t)255;
    hipMemsetAsync(cnt, 0, cpad + (size_t)NNODES * 4, stream);   // cnt + cur in one fill

    count_cast<<<NB_COUNT + NB_CAST, 256, 0, stream>>>(col, cnt, W1, W2, w1t, w2t);
    const int nsb = (NNODES + SCAN_BS - 1) / SCAN_BS;            // 98 blocks
    scan_part <<<nsb, SCAN_BS, 0, stream>>>(cnt, bsum, NNODES);
    scan_top  <<<1, 128, 0, stream>>>(bsum, nsb);
    scan_apply<<<nsb, SCAN_BS, 0, stream>>>(cnt, bsum, rp, dinv, NNODES, NEDGES);
    fill_kernel<<<(NEDGES + 255) / 256, 256, 0, stream>>>(row, col, rp, cur, csrw, dinv, NEDGES);

    gemm1_fused<<<MPAD / 64, 256, 0, stream>>>(x, w1t, h_bf);
    agg_kernel<<<(NNODES + 3) / 4, 256, 0, stream>>>((const short8*)h_bf, (short8*)a_bf,
                                                     dinv, rp, csrw, b1, NNODES);
    gemm2_lds<<<MPAD / 64, 256, 0, stream>>>(a_bf, w2t, h_bf);
    agg2_mm3_kernel<<<(NNODES + 3) / 4, 256, 0, stream>>>((const short8*)h_bf, h3p,
                                                          dinv, rp, csrw, b2, W3, NNODES);
    final_kernel<<<(NNODES + 255) / 256, 256, 0, stream>>>(h3p, dinv, rp, csrw, b3, out, NNODES);
}

// Round 5
// 643.206 us; speedup vs baseline: 1.1211x; 1.1211x over previous
//
#include <hip/hip_runtime.h>
#include <math.h>

#define NNODES 50000
#define NEDGES 800000
#define FIN    1433
#define KP1    1472   // FIN padded to multiple of 64
#define HDIM   256
#define NCLS   7
#define MPAD   50048  // NNODES padded to multiple of 64
#define G1B    782    // MPAD/64 gemm1 tiles

typedef __attribute__((ext_vector_type(8))) short short8;
typedef __attribute__((ext_vector_type(4))) float f32x4;

__device__ __forceinline__ unsigned short f2bf(float f) {
    unsigned u = __builtin_bit_cast(unsigned, f);
    u += 0x7fffu + ((u >> 16) & 1u);          // round-to-nearest-even
    return (unsigned short)(u >> 16);
}

__device__ __forceinline__ float bf2f(unsigned short u) {
    unsigned v = ((unsigned)u) << 16;
    return __builtin_bit_cast(float, v);
}

__device__ __forceinline__ void gl2lds16(const void* g, void* l) {
    __builtin_amdgcn_global_load_lds(
        (const __attribute__((address_space(1))) unsigned int*)g,
        (__attribute__((address_space(3))) unsigned int*)l, 16, 0, 0);
}

// unaligned-safe 16 B load (X rows are only 4 B aligned: FIN=1433)
__device__ __forceinline__ f32x4 ld4u(const float* p) {
    f32x4 v; __builtin_memcpy(&v, p, 16); return v;
}

// ---------------- CSR count + weight transpose/cast, one launch ----------------

#define NB_COUNT 3125   // ceil(NEDGES/256)
#define NB_CAST  1728   // ceil((HDIM*KP1 + HDIM*HDIM)/256)

__global__ void count_cast(const int* __restrict__ col, int* __restrict__ cnt,
                           const float* __restrict__ W1, const float* __restrict__ W2,
                           unsigned short* __restrict__ w1t, unsigned short* __restrict__ w2t) {
    int b = blockIdx.x;
    if (b < NB_COUNT) {
        int e = b * 256 + threadIdx.x;
        if (e < NEDGES) atomicAdd(&cnt[col[e]], 1);
    } else {
        int idx = (b - NB_COUNT) * 256 + threadIdx.x;
        if (idx < HDIM * KP1) {
            int n = idx / KP1, k = idx % KP1;
            w1t[idx] = f2bf((k < FIN) ? W1[(size_t)k * HDIM + n] : 0.f);
        } else {
            int j = idx - HDIM * KP1;
            if (j < HDIM * HDIM) {
                int n = j / HDIM, k = j % HDIM;
                w2t[j] = f2bf(W2[(size_t)k * HDIM + n]);
            }
        }
    }
}

// 2-stage parallel scan (top-scan folded into apply: 98 partials, redundant per block)
#define SCAN_BS 512
#define NSB     98      // ceil(NNODES/SCAN_BS)

__global__ __launch_bounds__(SCAN_BS) void scan_part(const int* __restrict__ cnt,
                                                     int* __restrict__ bsum, int n) {
    __shared__ int red[SCAN_BS];
    int t = threadIdx.x;
    int i = blockIdx.x * SCAN_BS + t;
    red[t] = (i < n) ? cnt[i] : 0;
    __syncthreads();
    for (int off = SCAN_BS / 2; off > 0; off >>= 1) {
        if (t < off) red[t] += red[t + off];
        __syncthreads();
    }
    if (t == 0) bsum[blockIdx.x] = red[0];
}

__global__ __launch_bounds__(SCAN_BS) void scan_apply(const int* __restrict__ cnt,
                                                      const int* __restrict__ bsum,
                                                      int* __restrict__ rp,
                                                      float* __restrict__ dinv,
                                                      int n, int total) {
    __shared__ int s[SCAN_BS];
    __shared__ int bs[128];
    __shared__ int base;
    int t = threadIdx.x;
    if (t < 128) bs[t] = (t < NSB) ? bsum[t] : 0;
    int i = blockIdx.x * SCAN_BS + t;
    int v = (i < n) ? cnt[i] : 0;
    s[t] = v;
    __syncthreads();
    if (t == 0) {                               // ~97 LDS adds, negligible
        int acc = 0;
        for (int j = 0; j < blockIdx.x; ++j) acc += bs[j];
        base = acc;
    }
    for (int off = 1; off < SCAN_BS; off <<= 1) {
        int u = (t >= off) ? s[t - off] : 0;
        __syncthreads();
        s[t] += u;
        __syncthreads();
    }
    if (i < n) {
        rp[i] = base + s[t] - v;                // exclusive prefix
        dinv[i] = rsqrtf((float)(v + 1));
    }
    if (i == n) rp[n] = total;
}

// ---------------- merged fill + layer-1 GEMM ----------------
// Blocks [0,G1B): gemm1 tiles (start immediately). Blocks [G1B, G1B+NB_COUNT): CSR fill
// (atomics + scattered 8B stores) backfilling CU idle slots under gemm1's memory waits.
// Independent data: gemm1 reads x/w1t, fill reads ei/rp/dinv -> no intra-kernel ordering.

__global__ __launch_bounds__(256) void fill_gemm1(const float* __restrict__ X,
                                                  const unsigned short* __restrict__ Bt,
                                                  unsigned short* __restrict__ C,
                                                  const int* __restrict__ row,
                                                  const int* __restrict__ col,
                                                  const int* __restrict__ rp,
                                                  int* __restrict__ cur,
                                                  int2* __restrict__ csrw,
                                                  const float* __restrict__ dinv) {
    __shared__ __align__(16) unsigned short As[64 * 64];    // 8 KB
    __shared__ __align__(16) unsigned short Bs[256 * 64];   // 32 KB

    if (blockIdx.x >= G1B) {                    // ---- fill branch ----
        int e = (blockIdx.x - G1B) * 256 + threadIdx.x;
        if (e < NEDGES) {
            int c = col[e], r = row[e];
            int pos = rp[c] + atomicAdd(&cur[c], 1);
            csrw[pos] = make_int2(r, __float_as_int(dinv[r] * dinv[c]));
        }
        return;
    }

    // ---- gemm1 branch (R2-verified: single-buffer, 1-deep X prefetch) ----
    const int tid = threadIdx.x;
    const int wave = tid >> 6, lane = tid & 63;
    const int m0 = blockIdx.x * 64;
    const int wn = wave * 64;
    const int kq = lane >> 4, l16 = lane & 15;
    const int lq = lane >> 4;      // row within 4-row group
    const int h  = lane & 15;      // k-quad index, 16 per row

    int rowbase[4];
    #pragma unroll
    for (int i = 0; i < 4; ++i) {
        int r = m0 + wave * 16 + i * 4 + lq;
        if (r >= NNODES) r = NNODES - 1;       // clamp: in-bounds, filtered at store
        rowbase[i] = r * FIN;
    }
    // LDS write offsets: row r = wave*16 + i*4 + lq -> r&7 = lq + 4*(i&1)
    int aw[4];
    #pragma unroll
    for (int i = 0; i < 4; ++i) {
        int r7 = lq + 4 * (i & 1);
        aw[i] = (wave * 16 + i * 4 + lq) * 64 + (((h >> 1) ^ r7) * 8) + (h & 1) * 4;
    }

    int bo[8];
    #pragma unroll
    for (int i = 0; i < 8; ++i) {
        int c = i * 256 + tid;                 // LDS chunk = linear c
        int n = c >> 3, ccg = (c & 7) ^ (n & 7);
        bo[i] = n * KP1 + ccg * 8;             // permuted global chunk
    }

    int aoffb[2], boffb[2];
    #pragma unroll
    for (int ks = 0; ks < 2; ++ks) {
        int swz = ((ks * 4 + kq) ^ (l16 & 7)) * 8;
        aoffb[ks] = l16 * 64 + swz;
        boffb[ks] = (wn + l16) * 64 + swz;
    }

    f32x4 acc[4][4] = {};
    constexpr int NT = KP1 / 64;               // 23 chunks; only the last crosses FIN

    f32x4 fv[4];
    #pragma unroll
    for (int i = 0; i < 4; ++i) fv[i] = ld4u(&X[rowbase[i] + h * 4]);   // chunk 0, k<64

    for (int t = 0; t < NT; ++t) {
        const int k0 = t * 64;
        #pragma unroll
        for (int i = 0; i < 8; ++i)
            gl2lds16(Bt + bo[i] + k0, &Bs[(i * 256 + tid) * 8]);
        #pragma unroll
        for (int i = 0; i < 4; ++i) {
            ushort4 pk = make_ushort4(f2bf(fv[i].x), f2bf(fv[i].y),
                                      f2bf(fv[i].z), f2bf(fv[i].w));
            *(ushort4*)&As[aw[i]] = pk;
        }
        __syncthreads();

        // prefetch chunk t+1 while the MFMAs below run (uniform branch)
        f32x4 nv[4];
        const bool more = (t + 1 < NT);
        if (more) {
            const int kb = k0 + 64 + h * 4;
            if (t + 2 == NT) {                 // last chunk: kb may reach 1468 >= FIN
                #pragma unroll
                for (int i = 0; i < 4; ++i) {
                    float a = (kb + 0 < FIN) ? X[rowbase[i] + kb + 0] : 0.f;
                    float b = (kb + 1 < FIN) ? X[rowbase[i] + kb + 1] : 0.f;
                    float c = (kb + 2 < FIN) ? X[rowbase[i] + kb + 2] : 0.f;
                    float d = (kb + 3 < FIN) ? X[rowbase[i] + kb + 3] : 0.f;
                    nv[i] = (f32x4){a, b, c, d};
                }
            } else {
                #pragma unroll
                for (int i = 0; i < 4; ++i) nv[i] = ld4u(&X[rowbase[i] + kb]);
            }
        }

        #pragma unroll
        for (int ks = 0; ks < 2; ++ks) {
            short8 af[4], bg[4];
            #pragma unroll
            for (int i = 0; i < 4; ++i) af[i] = *(const short8*)&As[i * 1024 + aoffb[ks]];
            #pragma unroll
            for (int j = 0; j < 4; ++j) bg[j] = *(const short8*)&Bs[j * 1024 + boffb[ks]];
            #pragma unroll
            for (int i = 0; i < 4; ++i)
                #pragma unroll
                for (int j = 0; j < 4; ++j)
                    acc[i][j] = __builtin_amdgcn_mfma_f32_16x16x32_bf16(af[i], bg[j], acc[i][j], 0, 0, 0);
        }
        __syncthreads();
        if (more) {
            #pragma unroll
            for (int i = 0; i < 4; ++i) fv[i] = nv[i];
        }
    }

    // C/D layout: col = lane&15, row = (lane>>4)*4 + reg
    #pragma unroll
    for (int i = 0; i < 4; ++i) {
        int gm_base = m0 + i * 16 + (lane >> 4) * 4;
        #pragma unroll
        for (int r = 0; r < 4; ++r) {
            int gm = gm_base + r;
            if (gm < NNODES) {
                #pragma unroll
                for (int j = 0; j < 4; ++j) {
                    int gn = wn + j * 16 + l16;
                    C[(size_t)gm * HDIM + gn] = f2bf(acc[i][j][r]);
                }
            }
        }
    }
}

// ---------------- layer-2 GEMM: bf16 A, all global_load_lds, BM=64 BN=256 BK=64 ----------

__global__ __launch_bounds__(256) void gemm2_lds(const unsigned short* __restrict__ A,
                                                 const unsigned short* __restrict__ Bt,
                                                 unsigned short* __restrict__ C) {
    __shared__ __align__(16) unsigned short As[64 * 64];
    __shared__ __align__(16) unsigned short Bs[256 * 64];
    const int tid = threadIdx.x;
    const int wave = tid >> 6, lane = tid & 63;
    const int m0 = blockIdx.x * 64;
    const int wn = wave * 64;
    const int kq = lane >> 4, l16 = lane & 15;

    int ao[2];
    #pragma unroll
    for (int i = 0; i < 2; ++i) {
        int c = i * 256 + tid;
        int m = c >> 3, ccg = (c & 7) ^ (m & 7);
        ao[i] = (m0 + m) * HDIM + ccg * 8;     // pad rows: finite poison, discarded at store
    }
    int bo[8];
    #pragma unroll
    for (int i = 0; i < 8; ++i) {
        int c = i * 256 + tid;
        int n = c >> 3, ccg = (c & 7) ^ (n & 7);
        bo[i] = n * HDIM + ccg * 8;
    }
    int aoffb[2], boffb[2];
    #pragma unroll
    for (int ks = 0; ks < 2; ++ks) {
        int swz = ((ks * 4 + kq) ^ (l16 & 7)) * 8;
        aoffb[ks] = l16 * 64 + swz;
        boffb[ks] = (wn + l16) * 64 + swz;
    }

    f32x4 acc[4][4] = {};
    #pragma unroll
    for (int k0 = 0; k0 < HDIM; k0 += 64) {
        #pragma unroll
        for (int i = 0; i < 2; ++i) gl2lds16(A + ao[i] + k0, &As[(i * 256 + tid) * 8]);
        #pragma unroll
        for (int i = 0; i < 8; ++i) gl2lds16(Bt + bo[i] + k0, &Bs[(i * 256 + tid) * 8]);
        __syncthreads();
        #pragma unroll
        for (int ks = 0; ks < 2; ++ks) {
            short8 af[4], bg[4];
            #pragma unroll
            for (int i = 0; i < 4; ++i) af[i] = *(const short8*)&As[i * 1024 + aoffb[ks]];
            #pragma unroll
            for (int j = 0; j < 4; ++j) bg[j] = *(const short8*)&Bs[j * 1024 + boffb[ks]];
            #pragma unroll
            for (int i = 0; i < 4; ++i)
                #pragma unroll
                for (int j = 0; j < 4; ++j)
                    acc[i][j] = __builtin_amdgcn_mfma_f32_16x16x32_bf16(af[i], bg[j], acc[i][j], 0, 0, 0);
        }
        __syncthreads();
    }

    #pragma unroll
    for (int i = 0; i < 4; ++i) {
        int gm_base = m0 + i * 16 + (lane >> 4) * 4;
        #pragma unroll
        for (int r = 0; r < 4; ++r) {
            int gm = gm_base + r;
            if (gm < NNODES) {
                #pragma unroll
                for (int j = 0; j < 4; ++j) {
                    int gn = wn + j * 16 + l16;
                    C[(size_t)gm * HDIM + gn] = f2bf(acc[i][j][r]);
                }
            }
        }
    }
}

// ---------------- shared aggregation inner loop (R2-proven: ushort4, unroll 8+4+1) -----

__device__ __forceinline__ void aggregate_row(const ushort4* __restrict__ h, int lane,
                                              int p, int p1,
                                              const int2* __restrict__ csrw,
                                              float& ax, float& ay, float& az, float& aw) {
    for (; p + 8 <= p1; p += 8) {
        int2 e[8];
        #pragma unroll
        for (int j = 0; j < 8; ++j) e[j] = csrw[p + j];
        ushort4 t[8];
        #pragma unroll
        for (int j = 0; j < 8; ++j) t[j] = h[e[j].x * 64 + lane];
        #pragma unroll
        for (int j = 0; j < 8; ++j) {
            float w = __int_as_float(e[j].y);
            ax += w * bf2f(t[j].x); ay += w * bf2f(t[j].y);
            az += w * bf2f(t[j].z); aw += w * bf2f(t[j].w);
        }
    }
    if (p + 4 <= p1) {
        int2 e[4];
        #pragma unroll
        for (int j = 0; j < 4; ++j) e[j] = csrw[p + j];
        ushort4 t[4];
        #pragma unroll
        for (int j = 0; j < 4; ++j) t[j] = h[e[j].x * 64 + lane];
        #pragma unroll
        for (int j = 0; j < 4; ++j) {
            float w = __int_as_float(e[j].y);
            ax += w * bf2f(t[j].x); ay += w * bf2f(t[j].y);
            az += w * bf2f(t[j].z); aw += w * bf2f(t[j].w);
        }
        p += 4;
    }
    for (; p < p1; ++p) {
        int2 e = csrw[p];
        float w = __int_as_float(e.y);
        ushort4 t = h[e.x * 64 + lane];
        ax += w * bf2f(t.x); ay += w * bf2f(t.y); az += w * bf2f(t.z); aw += w * bf2f(t.w);
    }
}

// ---------------- aggregation layer 1 (bf16 in/out, precomputed weights) ---------

__global__ __launch_bounds__(256) void agg_kernel(const ushort4* __restrict__ h,
                                                  ushort4* __restrict__ out,
                                                  const float* __restrict__ dinv,
                                                  const int* __restrict__ rp,
                                                  const int2* __restrict__ csrw,
                                                  const float* __restrict__ bias,
                                                  int n) {
    int node = blockIdx.x * 4 + (threadIdx.x >> 6);
    int lane = threadIdx.x & 63;
    if (node >= n) return;
    float di = dinv[node];
    float sw = di * di;
    ushort4 hv = h[node * 64 + lane];
    float ax = sw * bf2f(hv.x), ay = sw * bf2f(hv.y);
    float az = sw * bf2f(hv.z), aw = sw * bf2f(hv.w);
    aggregate_row(h, lane, rp[node], rp[node + 1], csrw, ax, ay, az, aw);
    float4 b = ((const float4*)bias)[lane];
    ax = fmaxf(ax + b.x, 0.f); ay = fmaxf(ay + b.y, 0.f);
    az = fmaxf(az + b.z, 0.f); aw = fmaxf(aw + b.w, 0.f);
    out[node * 64 + lane] = make_ushort4(f2bf(ax), f2bf(ay), f2bf(az), f2bf(aw));
}

// ---------------- aggregation layer 2 fused with mm3: h3p[N][8] (padded) ----------

__global__ __launch_bounds__(256) void agg2_mm3_kernel(const ushort4* __restrict__ h,
                                                       float* __restrict__ h3p,
                                                       const float* __restrict__ dinv,
                                                       const int* __restrict__ rp,
                                                       const int2* __restrict__ csrw,
                                                       const float* __restrict__ bias,
                                                       const float* __restrict__ W3,
                                                       int n) {
    __shared__ __align__(16) float Ws[NCLS * HDIM];   // Ws[c*256 + k] = W3[k*7 + c]
    int tid = threadIdx.x;
    for (int i = tid; i < NCLS * HDIM; i += 256)
        Ws[i] = W3[(i & 255) * NCLS + (i >> 8)];
    __syncthreads();

    int node = blockIdx.x * 4 + (tid >> 6);
    int lane = tid & 63;
    if (node >= n) return;
    float di = dinv[node];
    float sw = di * di;
    ushort4 hv = h[node * 64 + lane];
    float ax = sw * bf2f(hv.x), ay = sw * bf2f(hv.y);
    float az = sw * bf2f(hv.z), aw = sw * bf2f(hv.w);
    aggregate_row(h, lane, rp[node], rp[node + 1], csrw, ax, ay, az, aw);
    float4 b = ((const float4*)bias)[lane];
    ax = fmaxf(ax + b.x, 0.f); ay = fmaxf(ay + b.y, 0.f);
    az = fmaxf(az + b.z, 0.f); aw = fmaxf(aw + b.w, 0.f);

    float p7[NCLS];
    #pragma unroll
    for (int c = 0; c < NCLS; ++c) {
        float4 w4 = *(const float4*)&Ws[c * HDIM + 4 * lane];
        p7[c] = ax * w4.x + ay * w4.y + az * w4.z + aw * w4.w;
    }
    #pragma unroll
    for (int c = 0; c < NCLS; ++c)
        for (int off = 32; off > 0; off >>= 1) p7[c] += __shfl_down(p7[c], off);
    if (lane == 0) {
        *(float4*)&h3p[node * 8]     = make_float4(p7[0], p7[1], p7[2], p7[3]);
        *(float4*)&h3p[node * 8 + 4] = make_float4(p7[4], p7[5], p7[6], 0.f);
    }
}

// ---------------- layer-3 aggregation + bias + log_softmax (padded float4 reads) --------

__global__ void final_kernel(const float* __restrict__ h3p, const float* __restrict__ dinv,
                             const int* __restrict__ rp, const int2* __restrict__ csrw,
                             const float* __restrict__ b3, float* __restrict__ out, int n) {
    int i = blockIdx.x * blockDim.x + threadIdx.x;
    if (i >= n) return;
    const float4* H = (const float4*)h3p;
    float di = dinv[i];
    float sw = di * di;
    float4 su = H[i * 2], sv = H[i * 2 + 1];
    float a0 = sw * su.x, a1 = sw * su.y, a2 = sw * su.z, a3 = sw * su.w;
    float a4 = sw * sv.x, a5 = sw * sv.y, a6 = sw * sv.z;
    int p = rp[i], p1 = rp[i + 1];
    for (; p + 4 <= p1; p += 4) {
        int2 e0 = csrw[p], e1 = csrw[p + 1], e2 = csrw[p + 2], e3 = csrw[p + 3];
        float w0 = __int_as_float(e0.y), w1 = __int_as_float(e1.y);
        float w2 = __int_as_float(e2.y), w3 = __int_as_float(e3.y);
        float4 u0 = H[e0.x * 2], v0 = H[e0.x * 2 + 1];
        float4 u1 = H[e1.x * 2], v1 = H[e1.x * 2 + 1];
        float4 u2 = H[e2.x * 2], v2 = H[e2.x * 2 + 1];
        float4 u3 = H[e3.x * 2], v3 = H[e3.x * 2 + 1];
        a0 += w0 * u0.x + w1 * u1.x + w2 * u2.x + w3 * u3.x;
        a1 += w0 * u0.y + w1 * u1.y + w2 * u2.y + w3 * u3.y;
        a2 += w0 * u0.z + w1 * u1.z + w2 * u2.z + w3 * u3.z;
        a3 += w0 * u0.w + w1 * u1.w + w2 * u2.w + w3 * u3.w;
        a4 += w0 * v0.x + w1 * v1.x + w2 * v2.x + w3 * v3.x;
        a5 += w0 * v0.y + w1 * v1.y + w2 * v2.y + w3 * v3.y;
        a6 += w0 * v0.z + w1 * v1.z + w2 * v2.z + w3 * v3.z;
    }
    for (; p < p1; ++p) {
        int2 e = csrw[p];
        float wg = __int_as_float(e.y);
        float4 u = H[e.x * 2], v = H[e.x * 2 + 1];
        a0 += wg * u.x; a1 += wg * u.y; a2 += wg * u.z; a3 += wg * u.w;
        a4 += wg * v.x; a5 += wg * v.y; a6 += wg * v.z;
    }
    float acc[NCLS] = {a0, a1, a2, a3, a4, a5, a6};
    float mx = -1e30f;
    #pragma unroll
    for (int c = 0; c < NCLS; ++c) { acc[c] += b3[c]; mx = fmaxf(mx, acc[c]); }
    float sum = 0.f;
    #pragma unroll
    for (int c = 0; c < NCLS; ++c) sum += expf(acc[c] - mx);
    float lse = mx + logf(sum);
    #pragma unroll
    for (int c = 0; c < NCLS; ++c) out[i * NCLS + c] = acc[c] - lse;
}

// ---------------- launch ----------------

extern "C" void kernel_launch(void* const* d_in, const int* in_sizes, int n_in,
                              void* d_out, int out_size, void* d_ws, size_t ws_size,
                              hipStream_t stream) {
    const float* x  = (const float*)d_in[0];
    const int*   ei = (const int*)d_in[1];
    const float* W1 = (const float*)d_in[2];
    const float* b1 = (const float*)d_in[3];
    const float* W2 = (const float*)d_in[4];
    const float* b2 = (const float*)d_in[5];
    const float* W3 = (const float*)d_in[6];
    const float* b3 = (const float*)d_in[7];
    float* out = (float*)d_out;
    const int* row = ei;
    const int* col = ei + NEDGES;

    char* w = (char*)d_ws;
    auto alloc = [&](size_t b) { void* p = (void*)w; w += (b + 255) & ~(size_t)255; return p; };
    int*   cnt  = (int*)alloc(NNODES * 4);
    int*   cur  = (int*)alloc(NNODES * 4);   // contiguous with cnt (both 256-padded)
    int*   rp   = (int*)alloc((NNODES + 1) * 4);
    float* dinv = (float*)alloc(NNODES * 4);
    int*   bsum = (int*)alloc(128 * 4);
    int2*  csrw = (int2*)alloc((size_t)NEDGES * 8);
    unsigned short* w1t  = (unsigned short*)alloc((size_t)HDIM * KP1 * 2);
    unsigned short* w2t  = (unsigned short*)alloc((size_t)HDIM * HDIM * 2);
    unsigned short* h_bf = (unsigned short*)alloc((size_t)MPAD * HDIM * 2);
    unsigned short* a_bf = (unsigned short*)alloc((size_t)MPAD * HDIM * 2);
    float* h3p = (float*)alloc((size_t)NNODES * 8 * 4);

    const size_t cpad = ((size_t)NNODES * 4 + 255) & ~(size_t)255;
    hipMemsetAsync(cnt, 0, cpad + (size_t)NNODES * 4, stream);   // cnt + cur in one fill

    count_cast<<<NB_COUNT + NB_CAST, 256, 0, stream>>>(col, cnt, W1, W2, w1t, w2t);
    scan_part <<<NSB, SCAN_BS, 0, stream>>>(cnt, bsum, NNODES);
    scan_apply<<<NSB, SCAN_BS, 0, stream>>>(cnt, bsum, rp, dinv, NNODES, NEDGES);

    fill_gemm1<<<G1B + NB_COUNT, 256, 0, stream>>>(x, w1t, h_bf, row, col, rp, cur, csrw, dinv);

    agg_kernel<<<(NNODES + 3) / 4, 256, 0, stream>>>((const ushort4*)h_bf, (ushort4*)a_bf,
                                                     dinv, rp, csrw, b1, NNODES);
    gemm2_lds<<<MPAD / 64, 256, 0, stream>>>(a_bf, w2t, h_bf);
    agg2_mm3_kernel<<<(NNODES + 3) / 4, 256, 0, stream>>>((const ushort4*)h_bf, h3p,
                                                          dinv, rp, csrw, b2, W3, NNODES);
    final_kernel<<<(NNODES + 255) / 256, 256, 0, stream>>>(h3p, dinv, rp, csrw, b3, out, NNODES);
}